// Round 2
// baseline (463.603 us; speedup 1.0000x reference)
//
#include <hip/hip_runtime.h>
#include <math.h>

#define NEG_SLOPE 0.2f

__device__ __forceinline__ void fma4(float xv, const float4& wv, float* a) {
    a[0] += xv * wv.x; a[1] += xv * wv.y; a[2] += xv * wv.z; a[3] += xv * wv.w;
}

// ---------------------------------------------------------------- CSR build
__global__ void k_hist(const int* __restrict__ dst, int* __restrict__ deg, int E) {
    int e = blockIdx.x * 256 + threadIdx.x;
    if (e < E) atomicAdd(&deg[dst[e]], 1);
}

// chunk = 1024 elements per block (256 threads x 4)
__global__ void k_scan1(const int* __restrict__ deg, int* __restrict__ row_start,
                        int* __restrict__ partial, int n) {
    __shared__ int tmp[256];
    int t = threadIdx.x;
    int base = blockIdx.x * 1024 + t * 4;
    int v[4];
    int s = 0;
#pragma unroll
    for (int j = 0; j < 4; ++j) {
        v[j] = (base + j < n) ? deg[base + j] : 0;
        s += v[j];
    }
    tmp[t] = s;
    __syncthreads();
    for (int off = 1; off < 256; off <<= 1) {
        int xv = (t >= off) ? tmp[t - off] : 0;
        __syncthreads();
        tmp[t] += xv;
        __syncthreads();
    }
    int excl = tmp[t] - s;
    if (t == 255) partial[blockIdx.x] = tmp[255];
    int run = excl;
#pragma unroll
    for (int j = 0; j < 4; ++j) {
        if (base + j < n) row_start[base + j] = run;
        run += v[j];
    }
}

__global__ void k_scan2(int* __restrict__ partial, int nc) {
    __shared__ int tmp[128];
    int t = threadIdx.x;
    int v = (t < nc) ? partial[t] : 0;
    tmp[t] = v;
    __syncthreads();
    for (int off = 1; off < 128; off <<= 1) {
        int xv = (t >= off) ? tmp[t - off] : 0;
        __syncthreads();
        tmp[t] += xv;
        __syncthreads();
    }
    if (t < nc) partial[t] = tmp[t] - v;
}

__global__ void k_scan3(int* __restrict__ row_start, const int* __restrict__ partial,
                        int* __restrict__ cursor, int n, int E) {
    int i = blockIdx.x * 256 + threadIdx.x;
    if (i < n) {
        int r = row_start[i] + partial[i >> 10];
        row_start[i] = r;
        cursor[i] = r;
    }
    if (i == 0) row_start[n] = E;
}

__global__ void k_fill(const int* __restrict__ src, const int* __restrict__ dst,
                       int* __restrict__ cursor, int* __restrict__ csr_src, int E) {
    int e = blockIdx.x * 256 + threadIdx.x;
    if (e < E) {
        int d = dst[e];
        int p = atomicAdd(&cursor[d], 1);
        csr_src[p] = src[e];
    }
}

// ---------------------------------------------------------------- GEMM1: x@W1 -> feat1 [N,128], + el1/er1 [N,4]
__global__ __launch_bounds__(256) void gemm1(const float* __restrict__ x,
                                             const float* __restrict__ W,
                                             const float* __restrict__ al,
                                             const float* __restrict__ ar,
                                             float* __restrict__ feat,
                                             float* __restrict__ el,
                                             float* __restrict__ er, int n) {
    __shared__ float xs[32][132];
    __shared__ float ws[64][128];
    int t = threadIdx.x;
    int base = blockIdx.x * 32;
#pragma unroll
    for (int it = 0; it < 4; ++it) {
        int idx = it * 256 + t;
        int r = idx >> 5, q = idx & 31;
        float4 v = make_float4(0.f, 0.f, 0.f, 0.f);
        if (base + r < n) v = *(const float4*)&x[(size_t)(base + r) * 128 + q * 4];
        *(float4*)&xs[r][q * 4] = v;
    }
    int ty = t >> 5, tx = t & 31;
    int c0 = tx * 4;
    float acc[4][4] = {};
    for (int kc = 0; kc < 128; kc += 64) {
        __syncthreads();
#pragma unroll
        for (int it = 0; it < 8; ++it) {
            int idx = it * 256 + t;
            int kr = idx >> 5, q = idx & 31;
            *(float4*)&ws[kr][q * 4] = *(const float4*)&W[(size_t)(kc + kr) * 128 + q * 4];
        }
        __syncthreads();
#pragma unroll
        for (int k = 0; k < 64; k += 4) {
            float4 xq[4], wq[4];
#pragma unroll
            for (int i = 0; i < 4; ++i) xq[i] = *(float4*)&xs[ty * 4 + i][kc + k];
#pragma unroll
            for (int jj = 0; jj < 4; ++jj) wq[jj] = *(float4*)&ws[k + jj][c0];
#pragma unroll
            for (int i = 0; i < 4; ++i) {
                fma4(xq[i].x, wq[0], acc[i]);
                fma4(xq[i].y, wq[1], acc[i]);
                fma4(xq[i].z, wq[2], acc[i]);
                fma4(xq[i].w, wq[3], acc[i]);
            }
        }
    }
    float al4[4], ar4[4];
#pragma unroll
    for (int c = 0; c < 4; ++c) { al4[c] = al[c0 + c]; ar4[c] = ar[c0 + c]; }
    int head = tx >> 3;
#pragma unroll
    for (int i = 0; i < 4; ++i) {
        int row = base + ty * 4 + i;
        if (row >= n) continue;
        *(float4*)&feat[(size_t)row * 128 + c0] =
            make_float4(acc[i][0], acc[i][1], acc[i][2], acc[i][3]);
        float pl = acc[i][0] * al4[0] + acc[i][1] * al4[1] + acc[i][2] * al4[2] + acc[i][3] * al4[3];
        float pr = acc[i][0] * ar4[0] + acc[i][1] * ar4[1] + acc[i][2] * ar4[2] + acc[i][3] * ar4[3];
        pl += __shfl_xor(pl, 1); pl += __shfl_xor(pl, 2); pl += __shfl_xor(pl, 4);
        pr += __shfl_xor(pr, 1); pr += __shfl_xor(pr, 2); pr += __shfl_xor(pr, 4);
        if ((tx & 7) == 0) {
            el[row * 4 + head] = pl;
            er[row * 4 + head] = pr;
        }
    }
}

// ---------------------------------------------------------------- agg layer 1: per dst node, softmax + weighted sum, + bias + elu
__global__ __launch_bounds__(128) void agg1(const int* __restrict__ row_start,
                                            const int* __restrict__ csr_src,
                                            const float* __restrict__ el1,
                                            const float* __restrict__ er1,
                                            const float* __restrict__ feat1,
                                            const float* __restrict__ b1,
                                            float* __restrict__ hout) {
    int node = blockIdx.x;
    int t = threadIdx.x;      // 0..127
    int h = t >> 5, j = t & 31;
    __shared__ float evs[4][128];
    __shared__ int sns[128];
    int rs = row_start[node], re = row_start[node + 1];
    float er_h = er1[node * 4 + h];
    float m = -1e30f, zrun = 0.f, acc = 0.f;
    for (int ts = rs; ts < re; ts += 128) {
        int cnt = min(128, re - ts);
        __syncthreads();   // protect sns/evs from previous tile's readers
        if (t < cnt) sns[t] = csr_src[ts + t];
        __syncthreads();
        // tile max per head
        float pm = -1e30f;
        for (int idx = j; idx < cnt; idx += 32) {
            float ev = el1[sns[idx] * 4 + h] + er_h;
            ev = ev > 0.f ? ev : NEG_SLOPE * ev;
            evs[h][idx] = ev;
            pm = fmaxf(pm, ev);
        }
#pragma unroll
        for (int o = 16; o; o >>= 1) pm = fmaxf(pm, __shfl_xor(pm, o));
        // exp weights + tile sum
        float ps = 0.f;
        for (int idx = j; idx < cnt; idx += 32) {
            float u = __expf(evs[h][idx] - pm);
            evs[h][idx] = u;
            ps += u;
        }
#pragma unroll
        for (int o = 16; o; o >>= 1) ps += __shfl_xor(ps, o);
        __syncthreads();   // weights visible to all lanes
        float mnew = fmaxf(m, pm);
        float s_old = __expf(m - mnew);
        float s_t = __expf(pm - mnew);
        zrun = zrun * s_old + ps * s_t;
        float pacc = 0.f;
#pragma unroll 4
        for (int idx = 0; idx < cnt; ++idx)
            pacc += evs[h][idx] * feat1[(size_t)sns[idx] * 128 + t];
        acc = acc * s_old + pacc * s_t;
        m = mnew;
    }
    float rst = (zrun > 0.f) ? acc / zrun : 0.f;
    float v = rst + b1[t];
    hout[(size_t)node * 128 + t] = v > 0.f ? v : expm1f(v);
}

// ---------------------------------------------------------------- GEMM2: h@W2 -> feat2 [N,16], + el2/er2 [N]
__global__ __launch_bounds__(256) void gemm2(const float* __restrict__ hbuf,
                                             const float* __restrict__ W2,
                                             const float* __restrict__ al2,
                                             const float* __restrict__ ar2,
                                             float* __restrict__ feat2,
                                             float* __restrict__ el2,
                                             float* __restrict__ er2, int n) {
    __shared__ float hs[64][132];
    __shared__ float w2s[128][16];
    int t = threadIdx.x;
    int base = blockIdx.x * 64;
#pragma unroll
    for (int it = 0; it < 8; ++it) {
        int idx = it * 256 + t;
        int r = idx >> 5, q = idx & 31;
        int row = base + r;
        float4 v = make_float4(0.f, 0.f, 0.f, 0.f);
        if (row < n) v = *(const float4*)&hbuf[(size_t)row * 128 + q * 4];
        *(float4*)&hs[r][q * 4] = v;
    }
#pragma unroll
    for (int it = 0; it < 2; ++it) {
        int idx = it * 256 + t;   // 512 float4s
        int r = idx >> 2, cq = idx & 3;
        *(float4*)&w2s[r][cq * 4] = *(const float4*)&W2[r * 16 + cq * 4];
    }
    __syncthreads();
    int rl = t >> 2, c0 = (t & 3) * 4;
    float acc[4] = {};
#pragma unroll
    for (int k = 0; k < 128; k += 4) {
        float4 hv = *(float4*)&hs[rl][k];
        float4 w0 = *(float4*)&w2s[k][c0];
        float4 w1 = *(float4*)&w2s[k + 1][c0];
        float4 w2v = *(float4*)&w2s[k + 2][c0];
        float4 w3 = *(float4*)&w2s[k + 3][c0];
        acc[0] += hv.x * w0.x + hv.y * w1.x + hv.z * w2v.x + hv.w * w3.x;
        acc[1] += hv.x * w0.y + hv.y * w1.y + hv.z * w2v.y + hv.w * w3.y;
        acc[2] += hv.x * w0.z + hv.y * w1.z + hv.z * w2v.z + hv.w * w3.z;
        acc[3] += hv.x * w0.w + hv.y * w1.w + hv.z * w2v.w + hv.w * w3.w;
    }
    int row = base + rl;
    if (row < n) {
        *(float4*)&feat2[(size_t)row * 16 + c0] = make_float4(acc[0], acc[1], acc[2], acc[3]);
        float pl = acc[0] * al2[c0] + acc[1] * al2[c0 + 1] + acc[2] * al2[c0 + 2] + acc[3] * al2[c0 + 3];
        float pr = acc[0] * ar2[c0] + acc[1] * ar2[c0 + 1] + acc[2] * ar2[c0 + 2] + acc[3] * ar2[c0 + 3];
        pl += __shfl_xor(pl, 1); pl += __shfl_xor(pl, 2);
        pr += __shfl_xor(pr, 1); pr += __shfl_xor(pr, 2);
        if ((t & 3) == 0) { el2[row] = pl; er2[row] = pr; }
    }
}

// ---------------------------------------------------------------- agg layer 2: 1 wave per node, 16 output classes
__global__ __launch_bounds__(64) void agg2(const int* __restrict__ row_start,
                                           const int* __restrict__ csr_src,
                                           const float* __restrict__ el2,
                                           const float* __restrict__ er2,
                                           const float* __restrict__ feat2,
                                           const float* __restrict__ b2,
                                           float* __restrict__ out) {
    int node = blockIdx.x;
    int t = threadIdx.x;   // 0..63
    __shared__ float us[64];
    __shared__ int sns[64];
    int rs = row_start[node], re = row_start[node + 1];
    float er_n = er2[node];
    float m = -1e30f, zrun = 0.f, acc = 0.f;
    int c = t & 15, g = t >> 4;
    for (int ts = rs; ts < re; ts += 64) {
        int cnt = min(64, re - ts);
        __syncthreads();
        float ev = -1e30f;
        if (t < cnt) {
            int sn = csr_src[ts + t];
            sns[t] = sn;
            float e = el2[sn] + er_n;
            ev = e > 0.f ? e : NEG_SLOPE * e;
        }
        float pm = ev;
#pragma unroll
        for (int o = 32; o; o >>= 1) pm = fmaxf(pm, __shfl_xor(pm, o));
        float u = (t < cnt) ? __expf(ev - pm) : 0.f;
        us[t] = u;
        float ps = u;
#pragma unroll
        for (int o = 32; o; o >>= 1) ps += __shfl_xor(ps, o);
        __syncthreads();
        float mnew = fmaxf(m, pm);
        float s_old = __expf(m - mnew);
        float s_t = __expf(pm - mnew);
        zrun = zrun * s_old + ps * s_t;
        float pacc = 0.f;
        for (int idx = g; idx < cnt; idx += 4)
            pacc += us[idx] * feat2[(size_t)sns[idx] * 16 + c];
        acc = acc * s_old + pacc * s_t;
        m = mnew;
    }
    acc += __shfl_xor(acc, 16);
    acc += __shfl_xor(acc, 32);
    if (t < 16) {
        float rst = (zrun > 0.f) ? acc / zrun : 0.f;
        out[(size_t)node * 16 + t] = rst + b2[t];
    }
}

// ---------------------------------------------------------------- launch
extern "C" void kernel_launch(void* const* d_in, const int* in_sizes, int n_in,
                              void* d_out, int out_size, void* d_ws, size_t ws_size,
                              hipStream_t stream) {
    const float* x   = (const float*)d_in[0];
    const int*   src = (const int*)d_in[1];
    const int*   dst = (const int*)d_in[2];
    const float* W1  = (const float*)d_in[3];
    const float* al1 = (const float*)d_in[4];
    const float* ar1 = (const float*)d_in[5];
    const float* b1  = (const float*)d_in[6];
    const float* W2  = (const float*)d_in[7];
    const float* al2 = (const float*)d_in[8];
    const float* ar2 = (const float*)d_in[9];
    const float* b2  = (const float*)d_in[10];
    float* out = (float*)d_out;

    const int N = in_sizes[0] / 128;
    const int E = in_sizes[1];

    char* p = (char*)d_ws;
    auto alloc = [&](size_t bytes) {
        char* r = p;
        p += (bytes + 255) & ~(size_t)255;
        return r;
    };
    float* feat1 = (float*)alloc((size_t)N * 128 * 4);
    float* hbuf  = (float*)alloc((size_t)N * 128 * 4);
    float* feat2 = (float*)alloc((size_t)N * 16 * 4);
    float* el1   = (float*)alloc((size_t)N * 4 * 4);
    float* er1   = (float*)alloc((size_t)N * 4 * 4);
    float* el2v  = (float*)alloc((size_t)N * 4);
    float* er2v  = (float*)alloc((size_t)N * 4);
    int* row_start = (int*)alloc((size_t)(N + 1) * 4);
    int* cursor    = (int*)alloc((size_t)N * 4);
    int* csr_src   = (int*)alloc((size_t)E * 4);
    int* partial   = (int*)alloc(128 * 4);

    // CSR build (cursor doubles as degree array)
    (void)hipMemsetAsync(cursor, 0, (size_t)N * 4, stream);
    k_hist<<<(E + 255) / 256, 256, 0, stream>>>(dst, cursor, E);
    int nchunk = (N + 1023) / 1024;
    k_scan1<<<nchunk, 256, 0, stream>>>(cursor, row_start, partial, N);
    k_scan2<<<1, 128, 0, stream>>>(partial, nchunk);
    k_scan3<<<(N + 255) / 256, 256, 0, stream>>>(row_start, partial, cursor, N, E);
    k_fill<<<(E + 255) / 256, 256, 0, stream>>>(src, dst, cursor, csr_src, E);

    // layer 1
    gemm1<<<(N + 31) / 32, 256, 0, stream>>>(x, W1, al1, ar1, feat1, el1, er1, N);
    agg1<<<N, 128, 0, stream>>>(row_start, csr_src, el1, er1, feat1, b1, hbuf);

    // layer 2
    gemm2<<<(N + 63) / 64, 256, 0, stream>>>(hbuf, W2, al2, ar2, feat2, el2v, er2v, N);
    agg2<<<N, 64, 0, stream>>>(row_start, csr_src, el2v, er2v, feat2, b2, out);
}

// Round 3
// 412.528 us; speedup vs baseline: 1.1238x; 1.1238x over previous
//
#include <hip/hip_runtime.h>
#include <math.h>

#define NEG_SLOPE 0.2f

typedef unsigned short u16;
typedef float f32x4 __attribute__((ext_vector_type(4)));
typedef short s16x8 __attribute__((ext_vector_type(8)));

__device__ __forceinline__ u16 f2bf(float f) {
    unsigned u = __float_as_uint(f);
    unsigned r = (u + 0x7FFF + ((u >> 16) & 1)) >> 16;
    return (u16)r;
}
__device__ __forceinline__ float bf2f(u16 v) {
    return __uint_as_float((unsigned)v << 16);
}
// ushort-index XOR swizzle: flips byte bits 4-6 per row&7 -> conflict-free b128 col reads
#define SWZ(u, row) ((u) ^ (((row) & 7) << 3))

// ---------------------------------------------------------------- prep: augmented transposed bf16 weights
// W1bT [144][128]: c<128: W1[k][c]; c=128+h: sum_d W1[k][h*32+d]*al1[h][d]; c=132+h: ar1; else 0
// W2bT [32][128]:  c<16: W2[k][c]; c=16: sum W2[k][:]*al2; c=17: ar2; else 0
__global__ void prep(const float* __restrict__ W1, const float* __restrict__ al1,
                     const float* __restrict__ ar1, const float* __restrict__ W2,
                     const float* __restrict__ al2, const float* __restrict__ ar2,
                     u16* __restrict__ W1bT, u16* __restrict__ W2bT) {
    int t = threadIdx.x;
    for (int idx = t; idx < 144 * 128; idx += 256) {
        int c = idx >> 7, k = idx & 127;
        float v = 0.f;
        if (c < 128) v = W1[k * 128 + c];
        else if (c < 132) {
            int h = c - 128; float s = 0.f;
            for (int d = 0; d < 32; ++d) s += W1[k * 128 + h * 32 + d] * al1[h * 32 + d];
            v = s;
        } else if (c < 136) {
            int h = c - 132; float s = 0.f;
            for (int d = 0; d < 32; ++d) s += W1[k * 128 + h * 32 + d] * ar1[h * 32 + d];
            v = s;
        }
        W1bT[idx] = f2bf(v);
    }
    for (int idx = t; idx < 32 * 128; idx += 256) {
        int c = idx >> 7, k = idx & 127;
        float v = 0.f;
        if (c < 16) v = W2[k * 16 + c];
        else if (c == 16) { float s = 0.f; for (int d = 0; d < 16; ++d) s += W2[k * 16 + d] * al2[d]; v = s; }
        else if (c == 17) { float s = 0.f; for (int d = 0; d < 16; ++d) s += W2[k * 16 + d] * ar2[d]; v = s; }
        W2bT[idx] = f2bf(v);
    }
}

// ---------------------------------------------------------------- CSR build
__global__ void k_hist(const int* __restrict__ dst, int* __restrict__ deg, int E) {
    int e = blockIdx.x * 256 + threadIdx.x;
    if (e < E) atomicAdd(&deg[dst[e]], 1);
}

__global__ void k_scan1(const int* __restrict__ deg, int* __restrict__ row_start,
                        int* __restrict__ partial, int n) {
    __shared__ int tmp[256];
    int t = threadIdx.x;
    int base = blockIdx.x * 1024 + t * 4;
    int v[4];
    int s = 0;
#pragma unroll
    for (int j = 0; j < 4; ++j) {
        v[j] = (base + j < n) ? deg[base + j] : 0;
        s += v[j];
    }
    tmp[t] = s;
    __syncthreads();
    for (int off = 1; off < 256; off <<= 1) {
        int xv = (t >= off) ? tmp[t - off] : 0;
        __syncthreads();
        tmp[t] += xv;
        __syncthreads();
    }
    int excl = tmp[t] - s;
    if (t == 255) partial[blockIdx.x] = tmp[255];
    int run = excl;
#pragma unroll
    for (int j = 0; j < 4; ++j) {
        if (base + j < n) row_start[base + j] = run;
        run += v[j];
    }
}

__global__ void k_scan2(int* __restrict__ partial, int nc) {
    __shared__ int tmp[128];
    int t = threadIdx.x;
    int v = (t < nc) ? partial[t] : 0;
    tmp[t] = v;
    __syncthreads();
    for (int off = 1; off < 128; off <<= 1) {
        int xv = (t >= off) ? tmp[t - off] : 0;
        __syncthreads();
        tmp[t] += xv;
        __syncthreads();
    }
    if (t < nc) partial[t] = tmp[t] - v;
}

__global__ void k_scan3(int* __restrict__ row_start, const int* __restrict__ partial,
                        int* __restrict__ cursor, int n, int E) {
    int i = blockIdx.x * 256 + threadIdx.x;
    if (i < n) {
        int r = row_start[i] + partial[i >> 10];
        row_start[i] = r;
        cursor[i] = r;
    }
    if (i == 0) row_start[n] = E;
}

__global__ void k_fill(const int* __restrict__ src, const int* __restrict__ dst,
                       int* __restrict__ cursor, int* __restrict__ csr_src, int E) {
    int e = blockIdx.x * 256 + threadIdx.x;
    if (e < E) {
        int d = dst[e];
        int p = atomicAdd(&cursor[d], 1);
        csr_src[p] = src[e];
    }
}

// ---------------------------------------------------------------- GEMM1 (MFMA): x(f32->bf16) @ W1bT -> feat1b [N,128] bf16, el1/er1 [N,4] f32
__global__ __launch_bounds__(256) void gemm1_mfma(const float* __restrict__ x,
                                                  const u16* __restrict__ W1bT,
                                                  u16* __restrict__ featb,
                                                  float* __restrict__ el,
                                                  float* __restrict__ er, int n) {
    __shared__ u16 xs[64 * 128];
    __shared__ u16 ws[144 * 128];
    int t = threadIdx.x;
    int base = blockIdx.x * 64;
    // stage x rows -> bf16, swizzled
#pragma unroll
    for (int it = 0; it < 4; ++it) {
        int idx = it * 256 + t;              // 1024 chunks of 8
        int r = idx >> 4, c8 = (idx & 15) * 8;
        float4 v0 = make_float4(0.f, 0.f, 0.f, 0.f), v1 = v0;
        if (base + r < n) {
            v0 = *(const float4*)&x[(size_t)(base + r) * 128 + c8];
            v1 = *(const float4*)&x[(size_t)(base + r) * 128 + c8 + 4];
        }
        u16 tmp[8] = {f2bf(v0.x), f2bf(v0.y), f2bf(v0.z), f2bf(v0.w),
                      f2bf(v1.x), f2bf(v1.y), f2bf(v1.z), f2bf(v1.w)};
        *(s16x8*)&xs[SWZ(r * 128 + c8, r)] = *(s16x8*)tmp;
    }
    // stage W1bT (already bf16, row c = output col, contiguous k), swizzled
#pragma unroll
    for (int it = 0; it < 9; ++it) {
        int idx = it * 256 + t;              // 2304 chunks
        int c = idx >> 4, k8 = (idx & 15) * 8;
        *(s16x8*)&ws[SWZ(c * 128 + k8, c)] = *(const s16x8*)&W1bT[c * 128 + k8];
    }
    __syncthreads();
    int wid = t >> 6, lane = t & 63;
    int lr = lane & 15, lg = lane >> 4;
    int row0 = wid * 16;
    s16x8 afr[4];
#pragma unroll
    for (int kt = 0; kt < 4; ++kt) {
        int r = row0 + lr, k = kt * 32 + lg * 8;
        afr[kt] = *(const s16x8*)&xs[SWZ(r * 128 + k, r)];
    }
    f32x4 acc[9];
#pragma unroll
    for (int ct = 0; ct < 9; ++ct) acc[ct] = (f32x4){0.f, 0.f, 0.f, 0.f};
#pragma unroll
    for (int ct = 0; ct < 9; ++ct) {
#pragma unroll
        for (int kt = 0; kt < 4; ++kt) {
            int c = ct * 16 + lr, k = kt * 32 + lg * 8;
            s16x8 bfr = *(const s16x8*)&ws[SWZ(c * 128 + k, c)];
            acc[ct] = __builtin_amdgcn_mfma_f32_16x16x32_bf16(afr[kt], bfr, acc[ct], 0, 0, 0);
        }
    }
    // D[row][col]: col = ct*16+lr, row = row0 + lg*4 + r
#pragma unroll
    for (int ct = 0; ct < 9; ++ct) {
#pragma unroll
        for (int r = 0; r < 4; ++r) {
            int row = base + row0 + lg * 4 + r;
            if (row >= n) continue;
            float v = acc[ct][r];
            if (ct < 8) {
                featb[(size_t)row * 128 + ct * 16 + lr] = f2bf(v);
            } else {
                if (lr < 4) el[row * 4 + lr] = v;
                else if (lr < 8) er[row * 4 + (lr - 4)] = v;
            }
        }
    }
}

// ---------------------------------------------------------------- agg layer 1 (bf16 gather)
__global__ __launch_bounds__(128) void agg1(const int* __restrict__ row_start,
                                            const int* __restrict__ csr_src,
                                            const float* __restrict__ el1,
                                            const float* __restrict__ er1,
                                            const u16* __restrict__ featb,
                                            const float* __restrict__ b1,
                                            u16* __restrict__ hb) {
    int node = blockIdx.x;
    int t = threadIdx.x;      // 0..127
    int h = t >> 5, j = t & 31;
    __shared__ float evs[4][128];
    __shared__ int sns[128];
    int rs = row_start[node], re = row_start[node + 1];
    float er_h = er1[node * 4 + h];
    float m = -1e30f, zrun = 0.f, acc = 0.f;
    for (int ts = rs; ts < re; ts += 128) {
        int cnt = min(128, re - ts);
        __syncthreads();
        if (t < cnt) sns[t] = csr_src[ts + t];
        __syncthreads();
        float pm = -1e30f;
        for (int idx = j; idx < cnt; idx += 32) {
            float ev = el1[sns[idx] * 4 + h] + er_h;
            ev = ev > 0.f ? ev : NEG_SLOPE * ev;
            evs[h][idx] = ev;
            pm = fmaxf(pm, ev);
        }
#pragma unroll
        for (int o = 16; o; o >>= 1) pm = fmaxf(pm, __shfl_xor(pm, o));
        float ps = 0.f;
        for (int idx = j; idx < cnt; idx += 32) {
            float u = __expf(evs[h][idx] - pm);
            evs[h][idx] = u;
            ps += u;
        }
#pragma unroll
        for (int o = 16; o; o >>= 1) ps += __shfl_xor(ps, o);
        __syncthreads();
        float mnew = fmaxf(m, pm);
        float s_old = __expf(m - mnew);
        float s_t = __expf(pm - mnew);
        zrun = zrun * s_old + ps * s_t;
        float pacc = 0.f;
#pragma unroll 4
        for (int idx = 0; idx < cnt; ++idx)
            pacc += evs[h][idx] * bf2f(featb[(size_t)sns[idx] * 128 + t]);
        acc = acc * s_old + pacc * s_t;
        m = mnew;
    }
    float rst = (zrun > 0.f) ? acc / zrun : 0.f;
    float v = rst + b1[t];
    hb[(size_t)node * 128 + t] = f2bf(v > 0.f ? v : expm1f(v));
}

// ---------------------------------------------------------------- GEMM2 (MFMA): h(bf16) @ W2bT -> feat2b [N,16] bf16, el2/er2 [N] f32
__global__ __launch_bounds__(256) void gemm2_mfma(const u16* __restrict__ hb,
                                                  const u16* __restrict__ W2bT,
                                                  u16* __restrict__ feat2b,
                                                  float* __restrict__ el2,
                                                  float* __restrict__ er2, int n) {
    __shared__ u16 hs[64 * 128];
    __shared__ u16 ws[32 * 128];
    int t = threadIdx.x;
    int base = blockIdx.x * 64;
#pragma unroll
    for (int it = 0; it < 4; ++it) {
        int idx = it * 256 + t;              // 1024 chunks
        int r = idx >> 4, c8 = (idx & 15) * 8;
        s16x8 v = (s16x8){0, 0, 0, 0, 0, 0, 0, 0};
        if (base + r < n) v = *(const s16x8*)&hb[(size_t)(base + r) * 128 + c8];
        *(s16x8*)&hs[SWZ(r * 128 + c8, r)] = v;
    }
#pragma unroll
    for (int it = 0; it < 2; ++it) {
        int idx = it * 256 + t;              // 512 chunks
        int c = idx >> 4, k8 = (idx & 15) * 8;
        *(s16x8*)&ws[SWZ(c * 128 + k8, c)] = *(const s16x8*)&W2bT[c * 128 + k8];
    }
    __syncthreads();
    int wid = t >> 6, lane = t & 63;
    int lr = lane & 15, lg = lane >> 4;
    int row0 = wid * 16;
    s16x8 afr[4];
#pragma unroll
    for (int kt = 0; kt < 4; ++kt) {
        int r = row0 + lr, k = kt * 32 + lg * 8;
        afr[kt] = *(const s16x8*)&hs[SWZ(r * 128 + k, r)];
    }
    f32x4 acc[2];
    acc[0] = (f32x4){0.f, 0.f, 0.f, 0.f};
    acc[1] = acc[0];
#pragma unroll
    for (int ct = 0; ct < 2; ++ct) {
#pragma unroll
        for (int kt = 0; kt < 4; ++kt) {
            int c = ct * 16 + lr, k = kt * 32 + lg * 8;
            s16x8 bfr = *(const s16x8*)&ws[SWZ(c * 128 + k, c)];
            acc[ct] = __builtin_amdgcn_mfma_f32_16x16x32_bf16(afr[kt], bfr, acc[ct], 0, 0, 0);
        }
    }
#pragma unroll
    for (int ct = 0; ct < 2; ++ct) {
#pragma unroll
        for (int r = 0; r < 4; ++r) {
            int row = base + row0 + lg * 4 + r;
            if (row >= n) continue;
            float v = acc[ct][r];
            if (ct == 0) {
                feat2b[(size_t)row * 16 + lr] = f2bf(v);
            } else {
                if (lr == 0) el2[row] = v;
                else if (lr == 1) er2[row] = v;
            }
        }
    }
}

// ---------------------------------------------------------------- agg layer 2 (bf16 gather)
__global__ __launch_bounds__(64) void agg2(const int* __restrict__ row_start,
                                           const int* __restrict__ csr_src,
                                           const float* __restrict__ el2,
                                           const float* __restrict__ er2,
                                           const u16* __restrict__ feat2b,
                                           const float* __restrict__ b2,
                                           float* __restrict__ out) {
    int node = blockIdx.x;
    int t = threadIdx.x;   // 0..63
    __shared__ float us[64];
    __shared__ int sns[64];
    int rs = row_start[node], re = row_start[node + 1];
    float er_n = er2[node];
    float m = -1e30f, zrun = 0.f, acc = 0.f;
    int c = t & 15, g = t >> 4;
    for (int ts = rs; ts < re; ts += 64) {
        int cnt = min(64, re - ts);
        __syncthreads();
        float ev = -1e30f;
        if (t < cnt) {
            int sn = csr_src[ts + t];
            sns[t] = sn;
            float e = el2[sn] + er_n;
            ev = e > 0.f ? e : NEG_SLOPE * e;
        }
        float pm = ev;
#pragma unroll
        for (int o = 32; o; o >>= 1) pm = fmaxf(pm, __shfl_xor(pm, o));
        float u = (t < cnt) ? __expf(ev - pm) : 0.f;
        us[t] = u;
        float ps = u;
#pragma unroll
        for (int o = 32; o; o >>= 1) ps += __shfl_xor(ps, o);
        __syncthreads();
        float mnew = fmaxf(m, pm);
        float s_old = __expf(m - mnew);
        float s_t = __expf(pm - mnew);
        zrun = zrun * s_old + ps * s_t;
        float pacc = 0.f;
        for (int idx = g; idx < cnt; idx += 4)
            pacc += us[idx] * bf2f(feat2b[(size_t)sns[idx] * 16 + c]);
        acc = acc * s_old + pacc * s_t;
        m = mnew;
    }
    acc += __shfl_xor(acc, 16);
    acc += __shfl_xor(acc, 32);
    if (t < 16) {
        float rst = (zrun > 0.f) ? acc / zrun : 0.f;
        out[(size_t)node * 16 + t] = rst + b2[t];
    }
}

// ---------------------------------------------------------------- launch
extern "C" void kernel_launch(void* const* d_in, const int* in_sizes, int n_in,
                              void* d_out, int out_size, void* d_ws, size_t ws_size,
                              hipStream_t stream) {
    const float* x   = (const float*)d_in[0];
    const int*   src = (const int*)d_in[1];
    const int*   dst = (const int*)d_in[2];
    const float* W1  = (const float*)d_in[3];
    const float* al1 = (const float*)d_in[4];
    const float* ar1 = (const float*)d_in[5];
    const float* b1  = (const float*)d_in[6];
    const float* W2  = (const float*)d_in[7];
    const float* al2 = (const float*)d_in[8];
    const float* ar2 = (const float*)d_in[9];
    const float* b2  = (const float*)d_in[10];
    float* out = (float*)d_out;

    const int N = in_sizes[0] / 128;
    const int E = in_sizes[1];

    char* p = (char*)d_ws;
    auto alloc = [&](size_t bytes) {
        char* r = p;
        p += (bytes + 255) & ~(size_t)255;
        return r;
    };
    u16* W1bT   = (u16*)alloc(144 * 128 * 2);
    u16* W2bT   = (u16*)alloc(32 * 128 * 2);
    u16* feat1b = (u16*)alloc((size_t)N * 128 * 2);
    u16* hb     = (u16*)alloc((size_t)N * 128 * 2);
    u16* feat2b = (u16*)alloc((size_t)N * 16 * 2);
    float* el1  = (float*)alloc((size_t)N * 4 * 4);
    float* er1  = (float*)alloc((size_t)N * 4 * 4);
    float* el2v = (float*)alloc((size_t)N * 4);
    float* er2v = (float*)alloc((size_t)N * 4);
    int* row_start = (int*)alloc((size_t)(N + 1) * 4);
    int* cursor    = (int*)alloc((size_t)N * 4);
    int* csr_src   = (int*)alloc((size_t)E * 4);
    int* partial   = (int*)alloc(128 * 4);

    prep<<<1, 256, 0, stream>>>(W1, al1, ar1, W2, al2, ar2, W1bT, W2bT);

    (void)hipMemsetAsync(cursor, 0, (size_t)N * 4, stream);
    k_hist<<<(E + 255) / 256, 256, 0, stream>>>(dst, cursor, E);
    int nchunk = (N + 1023) / 1024;
    k_scan1<<<nchunk, 256, 0, stream>>>(cursor, row_start, partial, N);
    k_scan2<<<1, 128, 0, stream>>>(partial, nchunk);
    k_scan3<<<(N + 255) / 256, 256, 0, stream>>>(row_start, partial, cursor, N, E);
    k_fill<<<(E + 255) / 256, 256, 0, stream>>>(src, dst, cursor, csr_src, E);

    int nb = (N + 63) / 64;
    gemm1_mfma<<<nb, 256, 0, stream>>>(x, W1bT, feat1b, el1, er1, N);
    agg1<<<N, 128, 0, stream>>>(row_start, csr_src, el1, er1, feat1b, b1, hb);
    gemm2_mfma<<<nb, 256, 0, stream>>>(hb, W2bT, feat2b, el2v, er2v, N);
    agg2<<<N, 64, 0, stream>>>(row_start, csr_src, el2v, er2v, feat2b, b2, out);
}

// Round 4
// 243.838 us; speedup vs baseline: 1.9013x; 1.6918x over previous
//
#include <hip/hip_runtime.h>
#include <math.h>

#define NEG_SLOPE 0.2f
#define BUCKET_BITS 9
#define BUCKET_SZ (1 << BUCKET_BITS)

typedef unsigned short u16;
typedef float f32x4 __attribute__((ext_vector_type(4)));
typedef short s16x8 __attribute__((ext_vector_type(8)));

__device__ __forceinline__ u16 f2bf(float f) {
    unsigned u = __float_as_uint(f);
    unsigned r = (u + 0x7FFF + ((u >> 16) & 1)) >> 16;
    return (u16)r;
}
__device__ __forceinline__ float bf2f(u16 v) {
    return __uint_as_float((unsigned)v << 16);
}
// ushort-index XOR swizzle: conflict-free b128 col reads
#define SWZ(u, row) ((u) ^ (((row) & 7) << 3))

// ---------------------------------------------------------------- prep: augmented transposed bf16 weights (+ zero bucket cursors)
__global__ void prep(const float* __restrict__ W1, const float* __restrict__ al1,
                     const float* __restrict__ ar1, const float* __restrict__ W2,
                     const float* __restrict__ al2, const float* __restrict__ ar2,
                     u16* __restrict__ W1bT, u16* __restrict__ W2bT,
                     int* __restrict__ bucket_cursor, int NB) {
    int gt = blockIdx.x * 256 + threadIdx.x;
    int stride = gridDim.x * 256;
    if (gt < NB) bucket_cursor[gt] = 0;
    for (int idx = gt; idx < 144 * 128; idx += stride) {
        int c = idx >> 7, k = idx & 127;
        float v = 0.f;
        if (c < 128) v = W1[k * 128 + c];
        else if (c < 132) {
            int h = c - 128; float s = 0.f;
            for (int d = 0; d < 32; ++d) s += W1[k * 128 + h * 32 + d] * al1[h * 32 + d];
            v = s;
        } else if (c < 136) {
            int h = c - 132; float s = 0.f;
            for (int d = 0; d < 32; ++d) s += W1[k * 128 + h * 32 + d] * ar1[h * 32 + d];
            v = s;
        }
        W1bT[idx] = f2bf(v);
    }
    for (int idx = gt; idx < 32 * 128; idx += stride) {
        int c = idx >> 7, k = idx & 127;
        float v = 0.f;
        if (c < 16) v = W2[k * 16 + c];
        else if (c == 16) { float s = 0.f; for (int d = 0; d < 16; ++d) s += W2[k * 16 + d] * al2[d]; v = s; }
        else if (c == 17) { float s = 0.f; for (int d = 0; d < 16; ++d) s += W2[k * 16 + d] * ar2[d]; v = s; }
        W2bT[idx] = f2bf(v);
    }
}

// ---------------------------------------------------------------- CSR build: bucketed counting sort
// b_scatter: edges -> per-bucket staging streams of (src, dst&511), 8B records
__global__ __launch_bounds__(256) void b_scatter(const int* __restrict__ src,
                                                 const int* __restrict__ dst,
                                                 int* __restrict__ bucket_cursor,
                                                 uint2* __restrict__ staging,
                                                 int E, int NB, int cap) {
    __shared__ int cnt[256], rbase[256], cnt2[256];
    int t = threadIdx.x;
    if (t < NB) { cnt[t] = 0; cnt2[t] = 0; }
    __syncthreads();
    int base_e = blockIdx.x * 4096;
    int d[16];
#pragma unroll
    for (int it = 0; it < 16; ++it) {
        int e = base_e + it * 256 + t;
        d[it] = (e < E) ? dst[e] : -1;
        if (d[it] >= 0) atomicAdd(&cnt[d[it] >> BUCKET_BITS], 1);
    }
    __syncthreads();
    if (t < NB && cnt[t] > 0) rbase[t] = atomicAdd(&bucket_cursor[t], cnt[t]);
    __syncthreads();
#pragma unroll
    for (int it = 0; it < 16; ++it) {
        int e = base_e + it * 256 + t;
        if (d[it] >= 0) {
            int b = d[it] >> BUCKET_BITS;
            int ofs = atomicAdd(&cnt2[b], 1);
            int pos = rbase[b] + ofs;
            if (pos < cap)
                staging[(size_t)b * cap + pos] =
                    make_uint2((unsigned)src[e], (unsigned)(d[it] & (BUCKET_SZ - 1)));
        }
    }
}

// b_scan: exclusive scan of bucket counts -> bucket_base; sentinel row_start[N]=E
__global__ void b_scan(const int* __restrict__ bucket_cursor, int* __restrict__ bucket_base,
                       int* __restrict__ row_start, int NB, int N, int E) {
    __shared__ int tmp[256];
    int t = threadIdx.x;
    int v = (t < NB) ? bucket_cursor[t] : 0;
    tmp[t] = v;
    __syncthreads();
    for (int off = 1; off < 256; off <<= 1) {
        int x = (t >= off) ? tmp[t - off] : 0;
        __syncthreads();
        tmp[t] += x;
        __syncthreads();
    }
    if (t < NB) bucket_base[t] = tmp[t] - v;
    if (t == 0) row_start[N] = E;
}

// b_build: per-bucket node histogram + scan + fill, all in LDS
__global__ __launch_bounds__(256) void b_build(const uint2* __restrict__ staging,
                                               const int* __restrict__ bucket_cursor,
                                               const int* __restrict__ bucket_base,
                                               int* __restrict__ row_start,
                                               int* __restrict__ csr_src, int N, int cap) {
    __shared__ int deg[BUCKET_SZ];
    __shared__ int cur[BUCKET_SZ];
    __shared__ int tmp[256];
    int b = blockIdx.x, t = threadIdx.x;
    int node0 = b << BUCKET_BITS;
    int nn = min(BUCKET_SZ, N - node0);
    int cnt = min(bucket_cursor[b], cap);
    int cbase = bucket_base[b];
    for (int i = t; i < nn; i += 256) deg[i] = 0;
    __syncthreads();
    const uint2* st = &staging[(size_t)b * cap];
    for (int i = t; i < cnt; i += 256) atomicAdd(&deg[st[i].y], 1);
    __syncthreads();
    // scan deg[0..nn) -> exclusive offsets (each thread handles 2 elems)
    int i0 = 2 * t, i1 = 2 * t + 1;
    int a0 = (i0 < nn) ? deg[i0] : 0;
    int a1 = (i1 < nn) ? deg[i1] : 0;
    int s = a0 + a1;
    tmp[t] = s;
    __syncthreads();
    for (int off = 1; off < 256; off <<= 1) {
        int x = (t >= off) ? tmp[t - off] : 0;
        __syncthreads();
        tmp[t] += x;
        __syncthreads();
    }
    int excl = tmp[t] - s;
    if (i0 < nn) { row_start[node0 + i0] = cbase + excl;      cur[i0] = excl; }
    if (i1 < nn) { row_start[node0 + i1] = cbase + excl + a0; cur[i1] = excl + a0; }
    __syncthreads();
    for (int i = t; i < cnt; i += 256) {
        uint2 e = st[i];
        int p = atomicAdd(&cur[e.y], 1);
        csr_src[cbase + p] = (int)e.x;
    }
}

// ---------------------------------------------------------------- GEMM1 (MFMA): x(f32->bf16) @ W1bT -> feat1b [N,128] bf16, el1/er1 [N,4] f32
__global__ __launch_bounds__(256) void gemm1_mfma(const float* __restrict__ x,
                                                  const u16* __restrict__ W1bT,
                                                  u16* __restrict__ featb,
                                                  float* __restrict__ el,
                                                  float* __restrict__ er, int n) {
    __shared__ u16 xs[64 * 128];
    __shared__ u16 ws[144 * 128];
    int t = threadIdx.x;
    int base = blockIdx.x * 64;
#pragma unroll
    for (int it = 0; it < 4; ++it) {
        int idx = it * 256 + t;
        int r = idx >> 4, c8 = (idx & 15) * 8;
        float4 v0 = make_float4(0.f, 0.f, 0.f, 0.f), v1 = v0;
        if (base + r < n) {
            v0 = *(const float4*)&x[(size_t)(base + r) * 128 + c8];
            v1 = *(const float4*)&x[(size_t)(base + r) * 128 + c8 + 4];
        }
        u16 tmp[8] = {f2bf(v0.x), f2bf(v0.y), f2bf(v0.z), f2bf(v0.w),
                      f2bf(v1.x), f2bf(v1.y), f2bf(v1.z), f2bf(v1.w)};
        *(s16x8*)&xs[SWZ(r * 128 + c8, r)] = *(s16x8*)tmp;
    }
#pragma unroll
    for (int it = 0; it < 9; ++it) {
        int idx = it * 256 + t;
        int c = idx >> 4, k8 = (idx & 15) * 8;
        *(s16x8*)&ws[SWZ(c * 128 + k8, c)] = *(const s16x8*)&W1bT[c * 128 + k8];
    }
    __syncthreads();
    int wid = t >> 6, lane = t & 63;
    int lr = lane & 15, lg = lane >> 4;
    int row0 = wid * 16;
    s16x8 afr[4];
#pragma unroll
    for (int kt = 0; kt < 4; ++kt) {
        int r = row0 + lr, k = kt * 32 + lg * 8;
        afr[kt] = *(const s16x8*)&xs[SWZ(r * 128 + k, r)];
    }
    f32x4 acc[9];
#pragma unroll
    for (int ct = 0; ct < 9; ++ct) acc[ct] = (f32x4){0.f, 0.f, 0.f, 0.f};
#pragma unroll
    for (int ct = 0; ct < 9; ++ct) {
#pragma unroll
        for (int kt = 0; kt < 4; ++kt) {
            int c = ct * 16 + lr, k = kt * 32 + lg * 8;
            s16x8 bfr = *(const s16x8*)&ws[SWZ(c * 128 + k, c)];
            acc[ct] = __builtin_amdgcn_mfma_f32_16x16x32_bf16(afr[kt], bfr, acc[ct], 0, 0, 0);
        }
    }
#pragma unroll
    for (int ct = 0; ct < 9; ++ct) {
#pragma unroll
        for (int r = 0; r < 4; ++r) {
            int row = base + row0 + lg * 4 + r;
            if (row >= n) continue;
            float v = acc[ct][r];
            if (ct < 8) {
                featb[(size_t)row * 128 + ct * 16 + lr] = f2bf(v);
            } else {
                if (lr < 4) el[row * 4 + lr] = v;
                else if (lr < 8) er[row * 4 + (lr - 4)] = v;
            }
        }
    }
}

// ---------------------------------------------------------------- agg layer 1 (bf16 gather)
__global__ __launch_bounds__(128) void agg1(const int* __restrict__ row_start,
                                            const int* __restrict__ csr_src,
                                            const float* __restrict__ el1,
                                            const float* __restrict__ er1,
                                            const u16* __restrict__ featb,
                                            const float* __restrict__ b1,
                                            u16* __restrict__ hb, int n) {
    int node = blockIdx.x;
    int t = threadIdx.x;
    int h = t >> 5, j = t & 31;
    __shared__ float evs[4][128];
    __shared__ int sns[128];
    int rs = row_start[node], re = row_start[node + 1];
    float er_h = er1[node * 4 + h];
    float m = -1e30f, zrun = 0.f, acc = 0.f;
    for (int ts = rs; ts < re; ts += 128) {
        int cnt = min(128, re - ts);
        __syncthreads();
        if (t < cnt) sns[t] = min(max(csr_src[ts + t], 0), n - 1);
        __syncthreads();
        float pm = -1e30f;
        for (int idx = j; idx < cnt; idx += 32) {
            float ev = el1[sns[idx] * 4 + h] + er_h;
            ev = ev > 0.f ? ev : NEG_SLOPE * ev;
            evs[h][idx] = ev;
            pm = fmaxf(pm, ev);
        }
#pragma unroll
        for (int o = 16; o; o >>= 1) pm = fmaxf(pm, __shfl_xor(pm, o));
        float ps = 0.f;
        for (int idx = j; idx < cnt; idx += 32) {
            float u = __expf(evs[h][idx] - pm);
            evs[h][idx] = u;
            ps += u;
        }
#pragma unroll
        for (int o = 16; o; o >>= 1) ps += __shfl_xor(ps, o);
        __syncthreads();
        float mnew = fmaxf(m, pm);
        float s_old = __expf(m - mnew);
        float s_t = __expf(pm - mnew);
        zrun = zrun * s_old + ps * s_t;
        float pacc = 0.f;
#pragma unroll 4
        for (int idx = 0; idx < cnt; ++idx)
            pacc += evs[h][idx] * bf2f(featb[(size_t)sns[idx] * 128 + t]);
        acc = acc * s_old + pacc * s_t;
        m = mnew;
    }
    float rst = (zrun > 0.f) ? acc / zrun : 0.f;
    float v = rst + b1[t];
    hb[(size_t)node * 128 + t] = f2bf(v > 0.f ? v : expm1f(v));
}

// ---------------------------------------------------------------- GEMM2 (MFMA)
__global__ __launch_bounds__(256) void gemm2_mfma(const u16* __restrict__ hb,
                                                  const u16* __restrict__ W2bT,
                                                  u16* __restrict__ feat2b,
                                                  float* __restrict__ el2,
                                                  float* __restrict__ er2, int n) {
    __shared__ u16 hs[64 * 128];
    __shared__ u16 ws[32 * 128];
    int t = threadIdx.x;
    int base = blockIdx.x * 64;
#pragma unroll
    for (int it = 0; it < 4; ++it) {
        int idx = it * 256 + t;
        int r = idx >> 4, c8 = (idx & 15) * 8;
        s16x8 v = (s16x8){0, 0, 0, 0, 0, 0, 0, 0};
        if (base + r < n) v = *(const s16x8*)&hb[(size_t)(base + r) * 128 + c8];
        *(s16x8*)&hs[SWZ(r * 128 + c8, r)] = v;
    }
#pragma unroll
    for (int it = 0; it < 2; ++it) {
        int idx = it * 256 + t;
        int c = idx >> 4, k8 = (idx & 15) * 8;
        *(s16x8*)&ws[SWZ(c * 128 + k8, c)] = *(const s16x8*)&W2bT[c * 128 + k8];
    }
    __syncthreads();
    int wid = t >> 6, lane = t & 63;
    int lr = lane & 15, lg = lane >> 4;
    int row0 = wid * 16;
    s16x8 afr[4];
#pragma unroll
    for (int kt = 0; kt < 4; ++kt) {
        int r = row0 + lr, k = kt * 32 + lg * 8;
        afr[kt] = *(const s16x8*)&hs[SWZ(r * 128 + k, r)];
    }
    f32x4 acc[2];
    acc[0] = (f32x4){0.f, 0.f, 0.f, 0.f};
    acc[1] = acc[0];
#pragma unroll
    for (int ct = 0; ct < 2; ++ct) {
#pragma unroll
        for (int kt = 0; kt < 4; ++kt) {
            int c = ct * 16 + lr, k = kt * 32 + lg * 8;
            s16x8 bfr = *(const s16x8*)&ws[SWZ(c * 128 + k, c)];
            acc[ct] = __builtin_amdgcn_mfma_f32_16x16x32_bf16(afr[kt], bfr, acc[ct], 0, 0, 0);
        }
    }
#pragma unroll
    for (int ct = 0; ct < 2; ++ct) {
#pragma unroll
        for (int r = 0; r < 4; ++r) {
            int row = base + row0 + lg * 4 + r;
            if (row >= n) continue;
            float v = acc[ct][r];
            if (ct == 0) {
                feat2b[(size_t)row * 16 + lr] = f2bf(v);
            } else {
                if (lr == 0) el2[row] = v;
                else if (lr == 1) er2[row] = v;
            }
        }
    }
}

// ---------------------------------------------------------------- agg layer 2 (bf16 gather)
__global__ __launch_bounds__(64) void agg2(const int* __restrict__ row_start,
                                           const int* __restrict__ csr_src,
                                           const float* __restrict__ el2,
                                           const float* __restrict__ er2,
                                           const u16* __restrict__ feat2b,
                                           const float* __restrict__ b2,
                                           float* __restrict__ out, int n) {
    int node = blockIdx.x;
    int t = threadIdx.x;
    __shared__ float us[64];
    __shared__ int sns[64];
    int rs = row_start[node], re = row_start[node + 1];
    float er_n = er2[node];
    float m = -1e30f, zrun = 0.f, acc = 0.f;
    int c = t & 15, g = t >> 4;
    for (int ts = rs; ts < re; ts += 64) {
        int cnt = min(64, re - ts);
        __syncthreads();
        float ev = -1e30f;
        if (t < cnt) {
            int sn = min(max(csr_src[ts + t], 0), n - 1);
            sns[t] = sn;
            float e = el2[sn] + er_n;
            ev = e > 0.f ? e : NEG_SLOPE * e;
        }
        float pm = ev;
#pragma unroll
        for (int o = 32; o; o >>= 1) pm = fmaxf(pm, __shfl_xor(pm, o));
        float u = (t < cnt) ? __expf(ev - pm) : 0.f;
        us[t] = u;
        float ps = u;
#pragma unroll
        for (int o = 32; o; o >>= 1) ps += __shfl_xor(ps, o);
        __syncthreads();
        float mnew = fmaxf(m, pm);
        float s_old = __expf(m - mnew);
        float s_t = __expf(pm - mnew);
        zrun = zrun * s_old + ps * s_t;
        float pacc = 0.f;
        for (int idx = g; idx < cnt; idx += 4)
            pacc += us[idx] * bf2f(feat2b[(size_t)sns[idx] * 16 + c]);
        acc = acc * s_old + pacc * s_t;
        m = mnew;
    }
    acc += __shfl_xor(acc, 16);
    acc += __shfl_xor(acc, 32);
    if (t < 16) {
        float rst = (zrun > 0.f) ? acc / zrun : 0.f;
        out[(size_t)node * 16 + t] = rst + b2[t];
    }
}

// ---------------------------------------------------------------- launch
extern "C" void kernel_launch(void* const* d_in, const int* in_sizes, int n_in,
                              void* d_out, int out_size, void* d_ws, size_t ws_size,
                              hipStream_t stream) {
    const float* x   = (const float*)d_in[0];
    const int*   src = (const int*)d_in[1];
    const int*   dst = (const int*)d_in[2];
    const float* W1  = (const float*)d_in[3];
    const float* al1 = (const float*)d_in[4];
    const float* ar1 = (const float*)d_in[5];
    const float* b1  = (const float*)d_in[6];
    const float* W2  = (const float*)d_in[7];
    const float* al2 = (const float*)d_in[8];
    const float* ar2 = (const float*)d_in[9];
    const float* b2  = (const float*)d_in[10];
    float* out = (float*)d_out;

    const int N = in_sizes[0] / 128;
    const int E = in_sizes[1];
    const int NB = (N + BUCKET_SZ - 1) >> BUCKET_BITS;       // 196 buckets
    const int cap = ((2 * (E / NB)) + 255) & ~255;           // 2x mean, rounded

    char* p = (char*)d_ws;
    auto alloc = [&](size_t bytes) {
        char* r = p;
        p += (bytes + 255) & ~(size_t)255;
        return r;
    };
    u16* W1bT   = (u16*)alloc(144 * 128 * 2);
    u16* W2bT   = (u16*)alloc(32 * 128 * 2);
    u16* feat1b = (u16*)alloc((size_t)N * 128 * 2);
    u16* hb     = (u16*)alloc((size_t)N * 128 * 2);
    u16* feat2b = (u16*)alloc((size_t)N * 16 * 2);
    float* el1  = (float*)alloc((size_t)N * 4 * 4);
    float* er1  = (float*)alloc((size_t)N * 4 * 4);
    float* el2v = (float*)alloc((size_t)N * 4);
    float* er2v = (float*)alloc((size_t)N * 4);
    int* row_start     = (int*)alloc((size_t)(N + 1) * 4);
    int* csr_src       = (int*)alloc((size_t)E * 4);
    int* bucket_cursor = (int*)alloc((size_t)NB * 4);
    int* bucket_base   = (int*)alloc((size_t)NB * 4);
    uint2* staging     = (uint2*)alloc((size_t)NB * cap * 8);

    prep<<<72, 256, 0, stream>>>(W1, al1, ar1, W2, al2, ar2, W1bT, W2bT, bucket_cursor, NB);

    b_scatter<<<(E + 4095) / 4096, 256, 0, stream>>>(src, dst, bucket_cursor, staging, E, NB, cap);
    b_scan<<<1, 256, 0, stream>>>(bucket_cursor, bucket_base, row_start, NB, N, E);
    b_build<<<NB, 256, 0, stream>>>(staging, bucket_cursor, bucket_base, row_start, csr_src, N, cap);

    int nb = (N + 63) / 64;
    gemm1_mfma<<<nb, 256, 0, stream>>>(x, W1bT, feat1b, el1, er1, N);
    agg1<<<N, 128, 0, stream>>>(row_start, csr_src, el1, er1, feat1b, b1, hb, N);
    gemm2_mfma<<<nb, 256, 0, stream>>>(hb, W2bT, feat2b, el2v, er2v, N);
    agg2<<<N, 64, 0, stream>>>(row_start, csr_src, el2v, er2v, feat2b, b2, out, N);
}

// Round 5
// 199.837 us; speedup vs baseline: 2.3199x; 1.2202x over previous
//
#include <hip/hip_runtime.h>
#include <math.h>

#define NEG_SLOPE 0.2f
#define BUCKET_BITS 9
#define BUCKET_SZ (1 << BUCKET_BITS)

typedef unsigned short u16;
typedef float f32x4 __attribute__((ext_vector_type(4)));
typedef short s16x8 __attribute__((ext_vector_type(8)));

__device__ __forceinline__ u16 f2bf(float f) {
    unsigned u = __float_as_uint(f);
    unsigned r = (u + 0x7FFF + ((u >> 16) & 1)) >> 16;
    return (u16)r;
}
__device__ __forceinline__ float bf2f(u16 v) {
    return __uint_as_float((unsigned)v << 16);
}
// ushort-index XOR swizzle: conflict-free b128 col reads
#define SWZ(u, row) ((u) ^ (((row) & 7) << 3))

// ---------------------------------------------------------------- prep: augmented transposed bf16 weights (+ zero bucket cursors)
__global__ void prep(const float* __restrict__ W1, const float* __restrict__ al1,
                     const float* __restrict__ ar1, const float* __restrict__ W2,
                     const float* __restrict__ al2, const float* __restrict__ ar2,
                     u16* __restrict__ W1bT, u16* __restrict__ W2bT,
                     int* __restrict__ bucket_cursor, int NB) {
    int gt = blockIdx.x * 256 + threadIdx.x;
    int stride = gridDim.x * 256;
    if (gt < NB) bucket_cursor[gt] = 0;
    for (int idx = gt; idx < 144 * 128; idx += stride) {
        int c = idx >> 7, k = idx & 127;
        float v = 0.f;
        if (c < 128) v = W1[k * 128 + c];
        else if (c < 132) {
            int h = c - 128; float s = 0.f;
            for (int d = 0; d < 32; ++d) s += W1[k * 128 + h * 32 + d] * al1[h * 32 + d];
            v = s;
        } else if (c < 136) {
            int h = c - 132; float s = 0.f;
            for (int d = 0; d < 32; ++d) s += W1[k * 128 + h * 32 + d] * ar1[h * 32 + d];
            v = s;
        }
        W1bT[idx] = f2bf(v);
    }
    for (int idx = gt; idx < 32 * 128; idx += stride) {
        int c = idx >> 7, k = idx & 127;
        float v = 0.f;
        if (c < 16) v = W2[k * 16 + c];
        else if (c == 16) { float s = 0.f; for (int d = 0; d < 16; ++d) s += W2[k * 16 + d] * al2[d]; v = s; }
        else if (c == 17) { float s = 0.f; for (int d = 0; d < 16; ++d) s += W2[k * 16 + d] * ar2[d]; v = s; }
        W2bT[idx] = f2bf(v);
    }
}

// ---------------------------------------------------------------- CSR build: bucketed counting sort
__global__ __launch_bounds__(256) void b_scatter(const int* __restrict__ src,
                                                 const int* __restrict__ dst,
                                                 int* __restrict__ bucket_cursor,
                                                 uint2* __restrict__ staging,
                                                 int E, int NB, int cap) {
    __shared__ int cnt[256], rbase[256], cnt2[256];
    int t = threadIdx.x;
    if (t < NB) { cnt[t] = 0; cnt2[t] = 0; }
    __syncthreads();
    int base_e = blockIdx.x * 4096;
    int d[16];
#pragma unroll
    for (int it = 0; it < 16; ++it) {
        int e = base_e + it * 256 + t;
        d[it] = (e < E) ? dst[e] : -1;
        if (d[it] >= 0) atomicAdd(&cnt[d[it] >> BUCKET_BITS], 1);
    }
    __syncthreads();
    if (t < NB && cnt[t] > 0) rbase[t] = atomicAdd(&bucket_cursor[t], cnt[t]);
    __syncthreads();
#pragma unroll
    for (int it = 0; it < 16; ++it) {
        int e = base_e + it * 256 + t;
        if (d[it] >= 0) {
            int b = d[it] >> BUCKET_BITS;
            int ofs = atomicAdd(&cnt2[b], 1);
            int pos = rbase[b] + ofs;
            if (pos < cap)
                staging[(size_t)b * cap + pos] =
                    make_uint2((unsigned)src[e], (unsigned)(d[it] & (BUCKET_SZ - 1)));
        }
    }
}

__global__ void b_scan(const int* __restrict__ bucket_cursor, int* __restrict__ bucket_base,
                       int* __restrict__ row_start, int NB, int N, int E) {
    __shared__ int tmp[256];
    int t = threadIdx.x;
    int v = (t < NB) ? bucket_cursor[t] : 0;
    tmp[t] = v;
    __syncthreads();
    for (int off = 1; off < 256; off <<= 1) {
        int x = (t >= off) ? tmp[t - off] : 0;
        __syncthreads();
        tmp[t] += x;
        __syncthreads();
    }
    if (t < NB) bucket_base[t] = tmp[t] - v;
    if (t == 0) row_start[N] = E;
}

__global__ __launch_bounds__(256) void b_build(const uint2* __restrict__ staging,
                                               const int* __restrict__ bucket_cursor,
                                               const int* __restrict__ bucket_base,
                                               int* __restrict__ row_start,
                                               int* __restrict__ csr_src, int N, int cap) {
    __shared__ int deg[BUCKET_SZ];
    __shared__ int cur[BUCKET_SZ];
    __shared__ int tmp[256];
    int b = blockIdx.x, t = threadIdx.x;
    int node0 = b << BUCKET_BITS;
    int nn = min(BUCKET_SZ, N - node0);
    int cnt = min(bucket_cursor[b], cap);
    int cbase = bucket_base[b];
    for (int i = t; i < nn; i += 256) deg[i] = 0;
    __syncthreads();
    const uint2* st = &staging[(size_t)b * cap];
    for (int i = t; i < cnt; i += 256) atomicAdd(&deg[st[i].y], 1);
    __syncthreads();
    int i0 = 2 * t, i1 = 2 * t + 1;
    int a0 = (i0 < nn) ? deg[i0] : 0;
    int a1 = (i1 < nn) ? deg[i1] : 0;
    int s = a0 + a1;
    tmp[t] = s;
    __syncthreads();
    for (int off = 1; off < 256; off <<= 1) {
        int x = (t >= off) ? tmp[t - off] : 0;
        __syncthreads();
        tmp[t] += x;
        __syncthreads();
    }
    int excl = tmp[t] - s;
    if (i0 < nn) { row_start[node0 + i0] = cbase + excl;      cur[i0] = excl; }
    if (i1 < nn) { row_start[node0 + i1] = cbase + excl + a0; cur[i1] = excl + a0; }
    __syncthreads();
    for (int i = t; i < cnt; i += 256) {
        uint2 e = st[i];
        int p = atomicAdd(&cur[e.y], 1);
        csr_src[cbase + p] = (int)e.x;
    }
}

// ---------------------------------------------------------------- GEMM1 (MFMA)
__global__ __launch_bounds__(256) void gemm1_mfma(const float* __restrict__ x,
                                                  const u16* __restrict__ W1bT,
                                                  u16* __restrict__ featb,
                                                  float* __restrict__ el,
                                                  float* __restrict__ er, int n) {
    __shared__ u16 xs[64 * 128];
    __shared__ u16 ws[144 * 128];
    int t = threadIdx.x;
    int base = blockIdx.x * 64;
#pragma unroll
    for (int it = 0; it < 4; ++it) {
        int idx = it * 256 + t;
        int r = idx >> 4, c8 = (idx & 15) * 8;
        float4 v0 = make_float4(0.f, 0.f, 0.f, 0.f), v1 = v0;
        if (base + r < n) {
            v0 = *(const float4*)&x[(size_t)(base + r) * 128 + c8];
            v1 = *(const float4*)&x[(size_t)(base + r) * 128 + c8 + 4];
        }
        u16 tmp[8] = {f2bf(v0.x), f2bf(v0.y), f2bf(v0.z), f2bf(v0.w),
                      f2bf(v1.x), f2bf(v1.y), f2bf(v1.z), f2bf(v1.w)};
        *(s16x8*)&xs[SWZ(r * 128 + c8, r)] = *(s16x8*)tmp;
    }
#pragma unroll
    for (int it = 0; it < 9; ++it) {
        int idx = it * 256 + t;
        int c = idx >> 4, k8 = (idx & 15) * 8;
        *(s16x8*)&ws[SWZ(c * 128 + k8, c)] = *(const s16x8*)&W1bT[c * 128 + k8];
    }
    __syncthreads();
    int wid = t >> 6, lane = t & 63;
    int lr = lane & 15, lg = lane >> 4;
    int row0 = wid * 16;
    s16x8 afr[4];
#pragma unroll
    for (int kt = 0; kt < 4; ++kt) {
        int r = row0 + lr, k = kt * 32 + lg * 8;
        afr[kt] = *(const s16x8*)&xs[SWZ(r * 128 + k, r)];
    }
    f32x4 acc[9];
#pragma unroll
    for (int ct = 0; ct < 9; ++ct) acc[ct] = (f32x4){0.f, 0.f, 0.f, 0.f};
#pragma unroll
    for (int ct = 0; ct < 9; ++ct) {
#pragma unroll
        for (int kt = 0; kt < 4; ++kt) {
            int c = ct * 16 + lr, k = kt * 32 + lg * 8;
            s16x8 bfr = *(const s16x8*)&ws[SWZ(c * 128 + k, c)];
            acc[ct] = __builtin_amdgcn_mfma_f32_16x16x32_bf16(afr[kt], bfr, acc[ct], 0, 0, 0);
        }
    }
#pragma unroll
    for (int ct = 0; ct < 9; ++ct) {
#pragma unroll
        for (int r = 0; r < 4; ++r) {
            int row = base + row0 + lg * 4 + r;
            if (row >= n) continue;
            float v = acc[ct][r];
            if (ct < 8) {
                featb[(size_t)row * 128 + ct * 16 + lr] = f2bf(v);
            } else {
                if (lr < 4) el[row * 4 + lr] = v;
                else if (lr < 8) er[row * 4 + (lr - 4)] = v;
            }
        }
    }
}

// ---------------------------------------------------------------- agg layer 1: 1 wave/node, 4 nodes/block, no barriers/shuffles
__global__ __launch_bounds__(256) void agg1(const int* __restrict__ row_start,
                                            const int* __restrict__ csr_src,
                                            const float* __restrict__ el1,
                                            const float* __restrict__ er1,
                                            const u16* __restrict__ featb,
                                            const float* __restrict__ b1,
                                            u16* __restrict__ hb, int n) {
    __shared__ float us[4][64][4];   // [wave][edge][head]
    __shared__ int sns[4][64];
    int wid = threadIdx.x >> 6, lane = threadIdx.x & 63;
    int node = blockIdx.x * 4 + wid;
    if (node >= n) return;
    int rs = row_start[node], re = row_start[node + 1];
    float4 er4 = *(const float4*)&er1[node * 4];
    int h = lane >> 4;               // head of dims 2*lane, 2*lane+1
    float acc0 = 0.f, acc1 = 0.f, z = 0.f;
    for (int ts = rs; ts < re; ts += 64) {
        int cnt = min(64, re - ts);
        if (lane < cnt) {
            int sn = min(max(csr_src[ts + lane], 0), n - 1);
            sns[wid][lane] = sn;
            float4 elv = *(const float4*)&el1[sn * 4];
            float e0 = elv.x + er4.x, e1 = elv.y + er4.y;
            float e2 = elv.z + er4.z, e3 = elv.w + er4.w;
            e0 = e0 > 0.f ? e0 : NEG_SLOPE * e0;
            e1 = e1 > 0.f ? e1 : NEG_SLOPE * e1;
            e2 = e2 > 0.f ? e2 : NEG_SLOPE * e2;
            e3 = e3 > 0.f ? e3 : NEG_SLOPE * e3;
            float4 u4 = make_float4(__expf(fminf(e0, 60.f)), __expf(fminf(e1, 60.f)),
                                    __expf(fminf(e2, 60.f)), __expf(fminf(e3, 60.f)));
            *(float4*)&us[wid][lane][0] = u4;
        }
        for (int e = 0; e < cnt; ++e) {
            float w = us[wid][e][h];
            unsigned v = *(const unsigned*)&featb[(size_t)sns[wid][e] * 128 + lane * 2];
            acc0 += w * __uint_as_float(v << 16);
            acc1 += w * __uint_as_float(v & 0xffff0000u);
            z += w;
        }
    }
    float inv = (z > 0.f) ? 1.f / z : 0.f;
    float2 bv = *(const float2*)&b1[lane * 2];
    float v0 = acc0 * inv + bv.x;
    float v1 = acc1 * inv + bv.y;
    v0 = v0 > 0.f ? v0 : expm1f(v0);
    v1 = v1 > 0.f ? v1 : expm1f(v1);
    unsigned o = (unsigned)f2bf(v0) | ((unsigned)f2bf(v1) << 16);
    *(unsigned*)&hb[(size_t)node * 128 + lane * 2] = o;
}

// ---------------------------------------------------------------- GEMM2 (MFMA)
__global__ __launch_bounds__(256) void gemm2_mfma(const u16* __restrict__ hb,
                                                  const u16* __restrict__ W2bT,
                                                  u16* __restrict__ feat2b,
                                                  float* __restrict__ el2,
                                                  float* __restrict__ er2, int n) {
    __shared__ u16 hs[64 * 128];
    __shared__ u16 ws[32 * 128];
    int t = threadIdx.x;
    int base = blockIdx.x * 64;
#pragma unroll
    for (int it = 0; it < 4; ++it) {
        int idx = it * 256 + t;
        int r = idx >> 4, c8 = (idx & 15) * 8;
        s16x8 v = (s16x8){0, 0, 0, 0, 0, 0, 0, 0};
        if (base + r < n) v = *(const s16x8*)&hb[(size_t)(base + r) * 128 + c8];
        *(s16x8*)&hs[SWZ(r * 128 + c8, r)] = v;
    }
#pragma unroll
    for (int it = 0; it < 2; ++it) {
        int idx = it * 256 + t;
        int c = idx >> 4, k8 = (idx & 15) * 8;
        *(s16x8*)&ws[SWZ(c * 128 + k8, c)] = *(const s16x8*)&W2bT[c * 128 + k8];
    }
    __syncthreads();
    int wid = t >> 6, lane = t & 63;
    int lr = lane & 15, lg = lane >> 4;
    int row0 = wid * 16;
    s16x8 afr[4];
#pragma unroll
    for (int kt = 0; kt < 4; ++kt) {
        int r = row0 + lr, k = kt * 32 + lg * 8;
        afr[kt] = *(const s16x8*)&hs[SWZ(r * 128 + k, r)];
    }
    f32x4 acc[2];
    acc[0] = (f32x4){0.f, 0.f, 0.f, 0.f};
    acc[1] = acc[0];
#pragma unroll
    for (int ct = 0; ct < 2; ++ct) {
#pragma unroll
        for (int kt = 0; kt < 4; ++kt) {
            int c = ct * 16 + lr, k = kt * 32 + lg * 8;
            s16x8 bfr = *(const s16x8*)&ws[SWZ(c * 128 + k, c)];
            acc[ct] = __builtin_amdgcn_mfma_f32_16x16x32_bf16(afr[kt], bfr, acc[ct], 0, 0, 0);
        }
    }
#pragma unroll
    for (int ct = 0; ct < 2; ++ct) {
#pragma unroll
        for (int r = 0; r < 4; ++r) {
            int row = base + row0 + lg * 4 + r;
            if (row >= n) continue;
            float v = acc[ct][r];
            if (ct == 0) {
                feat2b[(size_t)row * 16 + lr] = f2bf(v);
            } else {
                if (lr == 0) el2[row] = v;
                else if (lr == 1) er2[row] = v;
            }
        }
    }
}

// ---------------------------------------------------------------- agg layer 2: 1 wave/node, 4 nodes/block
__global__ __launch_bounds__(256) void agg2(const int* __restrict__ row_start,
                                            const int* __restrict__ csr_src,
                                            const float* __restrict__ el2,
                                            const float* __restrict__ er2,
                                            const u16* __restrict__ feat2b,
                                            const float* __restrict__ b2,
                                            float* __restrict__ out, int n) {
    __shared__ float us[4][64];
    __shared__ int sns[4][64];
    int wid = threadIdx.x >> 6, lane = threadIdx.x & 63;
    int node = blockIdx.x * 4 + wid;
    if (node >= n) return;
    int rs = row_start[node], re = row_start[node + 1];
    float er_n = er2[node];
    int c = lane & 15, g = lane >> 4;
    float acc = 0.f, z = 0.f;
    for (int ts = rs; ts < re; ts += 64) {
        int cnt = min(64, re - ts);
        if (lane < cnt) {
            int sn = min(max(csr_src[ts + lane], 0), n - 1);
            sns[wid][lane] = sn;
            float e = el2[sn] + er_n;
            e = e > 0.f ? e : NEG_SLOPE * e;
            us[wid][lane] = __expf(fminf(e, 60.f));
        }
        for (int idx = g; idx < cnt; idx += 4) {
            float w = us[wid][idx];
            acc += w * bf2f(feat2b[(size_t)sns[wid][idx] * 16 + c]);
            z += w;
        }
    }
    acc += __shfl_xor(acc, 16);
    acc += __shfl_xor(acc, 32);
    z += __shfl_xor(z, 16);
    z += __shfl_xor(z, 32);
    if (lane < 16) {
        float rst = (z > 0.f) ? acc / z : 0.f;
        out[(size_t)node * 16 + lane] = rst + b2[lane];
    }
}

// ---------------------------------------------------------------- launch
extern "C" void kernel_launch(void* const* d_in, const int* in_sizes, int n_in,
                              void* d_out, int out_size, void* d_ws, size_t ws_size,
                              hipStream_t stream) {
    const float* x   = (const float*)d_in[0];
    const int*   src = (const int*)d_in[1];
    const int*   dst = (const int*)d_in[2];
    const float* W1  = (const float*)d_in[3];
    const float* al1 = (const float*)d_in[4];
    const float* ar1 = (const float*)d_in[5];
    const float* b1  = (const float*)d_in[6];
    const float* W2  = (const float*)d_in[7];
    const float* al2 = (const float*)d_in[8];
    const float* ar2 = (const float*)d_in[9];
    const float* b2  = (const float*)d_in[10];
    float* out = (float*)d_out;

    const int N = in_sizes[0] / 128;
    const int E = in_sizes[1];
    const int NB = (N + BUCKET_SZ - 1) >> BUCKET_BITS;
    const int cap = ((2 * (E / NB)) + 255) & ~255;

    char* p = (char*)d_ws;
    auto alloc = [&](size_t bytes) {
        char* r = p;
        p += (bytes + 255) & ~(size_t)255;
        return r;
    };
    u16* W1bT   = (u16*)alloc(144 * 128 * 2);
    u16* W2bT   = (u16*)alloc(32 * 128 * 2);
    u16* feat1b = (u16*)alloc((size_t)N * 128 * 2);
    u16* hb     = (u16*)alloc((size_t)N * 128 * 2);
    u16* feat2b = (u16*)alloc((size_t)N * 16 * 2);
    float* el1  = (float*)alloc((size_t)N * 4 * 4);
    float* er1  = (float*)alloc((size_t)N * 4 * 4);
    float* el2v = (float*)alloc((size_t)N * 4);
    float* er2v = (float*)alloc((size_t)N * 4);
    int* row_start     = (int*)alloc((size_t)(N + 1) * 4);
    int* csr_src       = (int*)alloc((size_t)E * 4);
    int* bucket_cursor = (int*)alloc((size_t)NB * 4);
    int* bucket_base   = (int*)alloc((size_t)NB * 4);
    uint2* staging     = (uint2*)alloc((size_t)NB * cap * 8);

    prep<<<72, 256, 0, stream>>>(W1, al1, ar1, W2, al2, ar2, W1bT, W2bT, bucket_cursor, NB);

    b_scatter<<<(E + 4095) / 4096, 256, 0, stream>>>(src, dst, bucket_cursor, staging, E, NB, cap);
    b_scan<<<1, 256, 0, stream>>>(bucket_cursor, bucket_base, row_start, NB, N, E);
    b_build<<<NB, 256, 0, stream>>>(staging, bucket_cursor, bucket_base, row_start, csr_src, N, cap);

    int nb = (N + 63) / 64;
    gemm1_mfma<<<nb, 256, 0, stream>>>(x, W1bT, feat1b, el1, er1, N);
    agg1<<<(N + 3) / 4, 256, 0, stream>>>(row_start, csr_src, el1, er1, feat1b, b1, hb, N);
    gemm2_mfma<<<nb, 256, 0, stream>>>(hb, W2bT, feat2b, el2v, er2v, N);
    agg2<<<(N + 3) / 4, 256, 0, stream>>>(row_start, csr_src, el2v, er2v, feat2b, b2, out, N);
}